// Round 8
// baseline (155.843 us; speedup 1.0000x reference)
//
#include <hip/hip_runtime.h>
#include <hip/hip_bf16.h>
#include <stdint.h>

#define N_NODES 16384   // B*H*W
#define NPB     4096    // nodes per batch
#define NB      4
#define KNN     4
#define NEDGE   (N_NODES * 5)
#define WIN     12      // sorted-order window radius for exact 1-D kNN
#define NBUK    4096

typedef short bf16x8 __attribute__((ext_vector_type(8)));
typedef float f32x4 __attribute__((ext_vector_type(4)));

__device__ __forceinline__ unsigned short f2bf(float f) {
  unsigned u = __float_as_uint(f);
  unsigned r = (u + 0x7fff + ((u >> 16) & 1)) >> 16;   // RNE
  return (unsigned short)r;
}
__device__ __forceinline__ float bf2f(unsigned short u) {
  return __uint_as_float(((unsigned)u) << 16);
}

// ---- block-wide exclusive scan of 4096 ints (1024 threads) ----
// part1 may alias cur (consumed before the final write phase, sync in between).
__device__ __forceinline__ void block_scan4096(const int* __restrict__ arr,
                                               int* __restrict__ dst,
                                               int* __restrict__ cur,
                                               int* __restrict__ part1,
                                               int* __restrict__ part2) {
  const int t = threadIdx.x;
  part1[t] = arr[4 * t + 0] + arr[4 * t + 1] + arr[4 * t + 2] + arr[4 * t + 3];
  __syncthreads();
  if (t < 64) {
    int s = 0;
#pragma unroll
    for (int k = 0; k < 16; ++k) s += part1[16 * t + k];
    part2[t] = s;
  }
  __syncthreads();
  if (t == 0) {
    int a = 0;
    for (int u = 0; u < 64; ++u) { int v = part2[u]; part2[u] = a; a += v; }
  }
  __syncthreads();
  int base = part2[t >> 4];
  for (int k = (t >> 4) * 16; k < t; ++k) base += part1[k];
  int a0 = arr[4 * t + 0], a1 = arr[4 * t + 1], a2 = arr[4 * t + 2], a3 = arr[4 * t + 3];
  __syncthreads();   // part1 fully consumed before cur (possible alias) is written
  dst[4 * t + 0] = base; cur[4 * t + 0] = base; base += a0;
  dst[4 * t + 1] = base; cur[4 * t + 1] = base; base += a1;
  dst[4 * t + 2] = base; cur[4 * t + 2] = base; base += a2;
  dst[4 * t + 3] = base; cur[4 * t + 3] = base; base += a3;
}

// ---- fused graph build: one block per batch ----
// counting sort by density bucket (monotone) + exact (value,idx) in-bucket order,
// windowed exact top-5 by (dist,idx), degree, CSR. Same semantics as R7 pipeline.
__global__ __launch_bounds__(1024)
void graph_build_kernel(const float* __restrict__ dm,
                        unsigned long long* __restrict__ skeys_g,
                        float* __restrict__ dinv_g,
                        int* __restrict__ off_g,
                        int* __restrict__ srcs_g) {
  __shared__ int sA[4096];   // bucket starts / offL
  __shared__ int sB[4096];   // bucket cur / curL  (part1 = sB[0..1024))
  __shared__ int sC[4096];   // hist, then deg
  __shared__ int sD[4096];   // rank            (part2 = sD[0..64))
  const int t = threadIdx.x;
  const int b = blockIdx.x;
  const float* d = dm + b * NPB;
  unsigned long long* kg = skeys_g + b * NPB;

  unsigned long long kv[4];
  // S1: zero hist, load (value,idx) keys
#pragma unroll
  for (int r = 0; r < 4; ++r) {
    int i = t + r * 1024;
    sC[i] = 0;
    float v = d[i];
    kv[r] = (((unsigned long long)__float_as_uint(v)) << 32) | (unsigned)i;
  }
  __syncthreads();
#pragma unroll
  for (int r = 0; r < 4; ++r) {
    float v = __uint_as_float((unsigned)(kv[r] >> 32));
    int bk = (int)(v * (float)NBUK); if (bk > NBUK - 1) bk = NBUK - 1;
    atomicAdd(&sC[bk], 1);
  }
  __syncthreads();
  // S2: scan hist -> sA (starts), sB (cur)
  block_scan4096(sC, sA, sB, sB, sD);
  __syncthreads();
  // S3: scatter keys to global slots
#pragma unroll
  for (int r = 0; r < 4; ++r) {
    float v = __uint_as_float((unsigned)(kv[r] >> 32));
    int bk = (int)(v * (float)NBUK); if (bk > NBUK - 1) bk = NBUK - 1;
    int slot = atomicAdd(&sB[bk], 1);
    kg[slot] = kv[r];
  }
  __syncthreads();
  // S4: in-bucket insertion sort (exact (value,idx) order) + rank; init deg=1
#pragma unroll
  for (int r = 0; r < 4; ++r) {
    int g = t + r * 1024;
    sC[g] = 1;   // deg init (hist dead after S2)
    int s0 = sA[g];
    int s1 = (g == NPB - 1) ? NPB : sA[g + 1];
    for (int i = s0 + 1; i < s1; ++i) {
      unsigned long long x = kg[i];
      int j = i - 1;
      while (j >= s0 && kg[j] > x) { kg[j + 1] = kg[j]; --j; }
      kg[j + 1] = x;
    }
    for (int i = s0; i < s1; ++i)
      sD[(int)(kg[i] & 0xffffffffull)] = i;
  }
  __syncthreads();
  // S5: windowed exact top-5 by (dist,idx); targets kept in registers
  unsigned long long tpack[4];
#pragma unroll
  for (int r = 0; r < 4; ++r) {
    int i = t + r * 1024;
    int p = sD[i];
    float di = __uint_as_float((unsigned)(kv[r] >> 32));
    int lo = p - WIN; if (lo < 0) lo = 0;
    int hi = p + WIN; if (hi > NPB - 1) hi = NPB - 1;
    unsigned long long k0 = ~0ull, k1 = ~0ull, k2 = ~0ull, k3 = ~0ull, k4 = ~0ull;
    for (int q = lo; q <= hi; ++q) {
      unsigned long long key = kg[q];
      float v = __uint_as_float((unsigned)(key >> 32));
      float dist = fabsf(di - v);
      unsigned long long dk = (((unsigned long long)__float_as_uint(dist)) << 32) |
                              (key & 0xffffffffull);
      if (dk < k4) {
        if (dk < k0)      { k4 = k3; k3 = k2; k2 = k1; k1 = k0; k0 = dk; }
        else if (dk < k1) { k4 = k3; k3 = k2; k2 = k1; k1 = dk; }
        else if (dk < k2) { k4 = k3; k3 = k2; k2 = dk; }
        else if (dk < k3) { k4 = k3; k3 = dk; }
        else              { k4 = dk; }
      }
    }
    int t0 = (int)(k1 & 0xffffffffull);
    int t1_ = (int)(k2 & 0xffffffffull);
    int t2_ = (int)(k3 & 0xffffffffull);
    int t3_ = (int)(k4 & 0xffffffffull);
    tpack[r] = (unsigned long long)(unsigned)t0 |
               ((unsigned long long)(unsigned)t1_ << 16) |
               ((unsigned long long)(unsigned)t2_ << 32) |
               ((unsigned long long)(unsigned)t3_ << 48);
    atomicAdd(&sC[t0], 1); atomicAdd(&sC[t1_], 1);
    atomicAdd(&sC[t2_], 1); atomicAdd(&sC[t3_], 1);
  }
  __syncthreads();
  // S6: scan deg -> sA (offL), sB (curL); write dinv/off
  block_scan4096(sC, sA, sB, sB, sD);
  __syncthreads();
#pragma unroll
  for (int r = 0; r < 4; ++r) {
    int i = t + r * 1024;
    dinv_g[b * NPB + i] = rsqrtf((float)sC[i]);
    off_g[b * NPB + i] = b * (NPB * 5) + sA[i];
  }
  if (b == NB - 1 && t == 0) off_g[N_NODES] = NEDGE;
  __syncthreads();
  // S7: CSR fill (4 kNN + self per node)
#pragma unroll
  for (int r = 0; r < 4; ++r) {
    int i = t + r * 1024;
    unsigned long long pk = tpack[r];
    int tg[5];
    tg[0] = (int)(pk & 0xffff);         tg[1] = (int)((pk >> 16) & 0xffff);
    tg[2] = (int)((pk >> 32) & 0xffff); tg[3] = (int)((pk >> 48) & 0xffff);
    tg[4] = i;
    int src = b * NPB + i;
#pragma unroll
    for (int q = 0; q < 5; ++q) {
      int pos = atomicAdd(&sB[tg[q]], 1);
      srcs_g[b * (NPB * 5) + pos] = src;
    }
  }
}

// ---- batched transpose + cvt bf16: [B][Rin][Cin]f32 -> [B][Cin][Rin]bf16 ----
__global__ void transpose_cvt_bf16_kernel(const float* __restrict__ in,
                                          unsigned short* __restrict__ out,
                                          int Rin, int Cin) {
  __shared__ float tile[32][33];
  int c0 = blockIdx.x * 32, r0 = blockIdx.y * 32, b = blockIdx.z;
  int tx = threadIdx.x & 31, ty = threadIdx.x >> 5;
  const float* ip = in + ((size_t)b * Rin + r0) * Cin + c0;
#pragma unroll
  for (int i = 0; i < 32; i += 8) tile[ty + i][tx] = ip[(size_t)(ty + i) * Cin + tx];
  __syncthreads();
  unsigned short* op = out + ((size_t)b * Cin + c0) * Rin + r0;
#pragma unroll
  for (int i = 0; i < 32; i += 8) op[(size_t)(ty + i) * Rin + tx] = f2bf(tile[tx][ty + i]);
}

// ---- propagate (bf16 in -> bf16 out), 4 nodes/block, C=256 ----
__global__ void prop_kernel(const unsigned short* __restrict__ in,
                            unsigned short* __restrict__ out,
                            const int* __restrict__ off, const int* __restrict__ srcs,
                            const float* __restrict__ dinv) {
  int i = blockIdx.x * 4 + (threadIdx.x >> 6);
  int l = threadIdx.x & 63;
  int e0 = off[i], e1 = off[i + 1];
  float ax = 0.f, ay = 0.f, az = 0.f, aw = 0.f;
  for (int e = e0; e < e1; ++e) {
    int j = srcs[e];
    float dj = dinv[j];
    ushort4 u = *(const ushort4*)(in + (size_t)j * 256 + l * 4);
    ax = fmaf(dj, bf2f(u.x), ax); ay = fmaf(dj, bf2f(u.y), ay);
    az = fmaf(dj, bf2f(u.z), az); aw = fmaf(dj, bf2f(u.w), aw);
  }
  float di = dinv[i];
  ushort4 o;
  o.x = f2bf(ax * di); o.y = f2bf(ay * di);
  o.z = f2bf(az * di); o.w = f2bf(aw * di);
  *(ushort4*)(out + (size_t)i * 256 + l * 4) = o;
}

// ---- fused propagate + bias + relu + transposed output write ----
// 64 nodes/block; accumulate in XOR-swizzled LDS, write out[b][c][n] coalesced.
__global__ __launch_bounds__(256)
void prop_out_kernel(const unsigned short* __restrict__ in,   // t2 bf16 [16384][256]
                     float* __restrict__ out,                 // [4][256][4096]
                     const int* __restrict__ off, const int* __restrict__ srcs,
                     const float* __restrict__ dinv, const float* __restrict__ bias) {
  __shared__ float ldsb[64 * 256];   // 64KB, [node][ch ^ (node&31)]
  int n0g = blockIdx.x * 64;
  int b = n0g >> 12;
  int n0l = n0g & (NPB - 1);
  int w = threadIdx.x >> 6, l = threadIdx.x & 63;
  float bv0 = bias[l * 4 + 0], bv1 = bias[l * 4 + 1];
  float bv2 = bias[l * 4 + 2], bv3 = bias[l * 4 + 3];
  for (int s = 0; s < 16; ++s) {
    int node = w * 16 + s;
    int i = n0g + node;
    int e0 = off[i], e1 = off[i + 1];
    float ax = 0.f, ay = 0.f, az = 0.f, aw = 0.f;
    for (int e = e0; e < e1; ++e) {
      int j = srcs[e];
      float dj = dinv[j];
      ushort4 u = *(const ushort4*)(in + (size_t)j * 256 + l * 4);
      ax = fmaf(dj, bf2f(u.x), ax); ay = fmaf(dj, bf2f(u.y), ay);
      az = fmaf(dj, bf2f(u.z), az); aw = fmaf(dj, bf2f(u.w), aw);
    }
    float di = dinv[i];
    int m = node & 31;
    float* row = ldsb + node * 256;
    row[(4 * l + 0) ^ m] = fmaxf(ax * di + bv0, 0.f);
    row[(4 * l + 1) ^ m] = fmaxf(ay * di + bv1, 0.f);
    row[(4 * l + 2) ^ m] = fmaxf(az * di + bv2, 0.f);
    row[(4 * l + 3) ^ m] = fmaxf(aw * di + bv3, 0.f);
  }
  __syncthreads();
  int g = l >> 4, k = l & 15;
  for (int it = 0; it < 16; ++it) {
    int c = w * 64 + it * 4 + g;
    float4 v;
    v.x = ldsb[(4 * k + 0) * 256 + (c ^ ((4 * k + 0) & 31))];
    v.y = ldsb[(4 * k + 1) * 256 + (c ^ ((4 * k + 1) & 31))];
    v.z = ldsb[(4 * k + 2) * 256 + (c ^ ((4 * k + 2) & 31))];
    v.w = ldsb[(4 * k + 3) * 256 + (c ^ ((4 * k + 3) & 31))];
    *(float4*)(out + ((size_t)b * 256 + c) * 4096 + n0l + 4 * k) = v;
  }
}

// ---- bf16 MFMA GEMM: C[M,N] = A[M,K] @ Bt[N,K]^T (+bias, relu) ----
template <bool BIAS_RELU, bool OUT_BF16>
__global__ __launch_bounds__(256)
void gemm_bf16_kernel(const unsigned short* __restrict__ A,
                      const unsigned short* __restrict__ Bt,
                      void* __restrict__ C, const float* __restrict__ bias,
                      int M, int N, int K) {
  __shared__ char lds[32768];
  const int tid = threadIdx.x;
  const int l = tid & 63, w = tid >> 6;
  const int bm = blockIdx.x * 128, bn = blockIdx.y * 128;
  const int wm = w >> 1, wn = w & 1;
  f32x4 acc[4][4] = {};

  for (int k0 = 0; k0 < K; k0 += 64) {
    __syncthreads();
#pragma unroll
    for (int q = 0; q < 4; ++q) {
      int o = q * 4096 + tid * 16;
      int r = o >> 7;
      int pc = (o >> 4) & 7;
      int gc = pc ^ (r & 7);
      const char* srcA = (const char*)A + ((size_t)(bm + r) * K + k0) * 2 + gc * 16;
      const char* srcB = (const char*)Bt + ((size_t)(bn + r) * K + k0) * 2 + gc * 16;
      __builtin_amdgcn_global_load_lds(
          (const __attribute__((address_space(1))) void*)srcA,
          (__attribute__((address_space(3))) void*)(lds + o), 16, 0, 0);
      __builtin_amdgcn_global_load_lds(
          (const __attribute__((address_space(1))) void*)srcB,
          (__attribute__((address_space(3))) void*)(lds + 16384 + o), 16, 0, 0);
    }
    __syncthreads();

#pragma unroll
    for (int kk = 0; kk < 64; kk += 32) {
      bf16x8 af[4], bf[4];
#pragma unroll
      for (int mi = 0; mi < 4; ++mi) {
        int r = wm * 64 + mi * 16 + (l & 15);
        int gc = (kk >> 3) + (l >> 4);
        af[mi] = *(const bf16x8*)(lds + r * 128 + ((gc ^ (r & 7)) << 4));
      }
#pragma unroll
      for (int ni = 0; ni < 4; ++ni) {
        int r = wn * 64 + ni * 16 + (l & 15);
        int gc = (kk >> 3) + (l >> 4);
        bf[ni] = *(const bf16x8*)(lds + 16384 + r * 128 + ((gc ^ (r & 7)) << 4));
      }
#pragma unroll
      for (int mi = 0; mi < 4; ++mi)
#pragma unroll
        for (int ni = 0; ni < 4; ++ni)
          acc[mi][ni] = __builtin_amdgcn_mfma_f32_16x16x32_bf16(af[mi], bf[ni],
                                                                acc[mi][ni], 0, 0, 0);
    }
  }

#pragma unroll
  for (int mi = 0; mi < 4; ++mi) {
#pragma unroll
    for (int ni = 0; ni < 4; ++ni) {
      int row0 = bm + wm * 64 + mi * 16 + ((l >> 4) << 2);
      int col = bn + wn * 64 + ni * 16 + (l & 15);
      float bv = BIAS_RELU ? bias[col] : 0.f;
      f32x4 v = acc[mi][ni];
#pragma unroll
      for (int r = 0; r < 4; ++r) {
        float val = v[r];
        if (BIAS_RELU) val = fmaxf(val + bv, 0.f);
        if (OUT_BF16)
          ((unsigned short*)C)[(size_t)(row0 + r) * N + col] = f2bf(val);
        else
          ((float*)C)[(size_t)(row0 + r) * N + col] = val;
      }
    }
  }
}

// ---- launch ----
extern "C" void kernel_launch(void* const* d_in, const int* in_sizes, int n_in,
                              void* d_out, int out_size, void* d_ws, size_t ws_size,
                              hipStream_t stream) {
  const float* dm = (const float*)d_in[0];
  const float* fm = (const float*)d_in[1];
  const float* W1 = (const float*)d_in[2];
  const float* b1 = (const float*)d_in[3];
  const float* W2 = (const float*)d_in[4];
  const float* b2 = (const float*)d_in[5];
  float* out = (float*)d_out;

  char* ws = (char*)d_ws;
  float*              dinv  = (float*)(ws + 0x000000);             // 64KB
  int*                off   = (int*)(ws + 0x010000);               // 64KB+4
  int*                srcs  = (int*)(ws + 0x030000);               // 320KB
  unsigned long long* skeys = (unsigned long long*)(ws + 0x080000);// 128KB
  unsigned short*     W1t   = (unsigned short*)(ws + 0x0A0000);    // 256KB
  unsigned short*     W2t   = (unsigned short*)(ws + 0x0E0000);    // 256KB
  unsigned short*     px0   = (unsigned short*)(ws + 0x0200000);   // 8MB
  unsigned short*     px    = (unsigned short*)(ws + 0x0A00000);   // 8MB
  unsigned short*     h1    = (unsigned short*)(ws + 0x1200000);   // 16MB
  unsigned short*     t2    = (unsigned short*)(ws + 0x2200000);   // 8MB
  (void)ws_size; (void)in_sizes; (void)n_in; (void)out_size;

  // graph build (counting sort + windowed exact kNN + CSR) — one kernel
  graph_build_kernel<<<NB, 1024, 0, stream>>>(dm, skeys, dinv, off, srcs);

  // weights -> bf16 [N][K]
  transpose_cvt_bf16_kernel<<<dim3(16, 8, 1), 256, 0, stream>>>(W1, W1t, 256, 512);
  transpose_cvt_bf16_kernel<<<dim3(8, 16, 1), 256, 0, stream>>>(W2, W2t, 512, 256);

  // feature maps -> node-major bf16
  transpose_cvt_bf16_kernel<<<dim3(128, 8, NB), 256, 0, stream>>>(fm, px0, 256, 4096);

  // layer 1: propagate then GEMM relu(.@W1+b1) -> bf16
  prop_kernel<<<N_NODES / 4, 256, 0, stream>>>(px0, px, off, srcs, dinv);
  gemm_bf16_kernel<true, true><<<dim3(128, 4), 256, 0, stream>>>(
      px, W1t, h1, b1, 16384, 512, 256);

  // layer 2: GEMM h1@W2 -> bf16, then fused propagate+bias+relu+transposed store
  gemm_bf16_kernel<false, true><<<dim3(128, 2), 256, 0, stream>>>(
      h1, W2t, t2, nullptr, 16384, 256, 512);
  prop_out_kernel<<<N_NODES / 64, 256, 0, stream>>>(t2, out, off, srcs, dinv, b2);
}